// Round 7
// baseline (430.008 us; speedup 1.0000x reference)
//
#include <hip/hip_runtime.h>
#include <cstdint>
#include <cstddef>

// GCN: h1 = relu(Â (x W1) + b1); h2 = relu(Â (h1 W2) + b2);
// g = mean-pool(h2 by batch); out = log_softmax(relu(g Wl1 + bl1) Wl2 + bl2)
// Â = D^-1/2 (A + I) D^-1/2.
//
// R7: dense transform distributes over aggregation:
//   Sum_r dis[r]*(h[r]@W) = (Sum_r dis[r]*h[r]) @ W
// so both standalone GEMMs are deleted; each gather applies W once per node
// after the reduce (LDS-staged transposed W, ds_read_b128 conflict-free via
// 17-float4 row pitch; aggregated row broadcast via v_readlane — no barrier).
// Dispatch count 12 -> 7 (scan fused into bhist last-block; s0 emit fused
// into place2; pool+head fused).

#define HF 64          // feature width
#define BSH 9          // bucket shift: 512 nodes per bucket
#define BSZ 512
#define PCHUNK 8192    // edges per k_part block
#define CAP 12288      // LDS out capacity in k_place2

typedef unsigned u32;

__device__ __forceinline__ unsigned short f2bf(float x) {
    unsigned u = __float_as_uint(x);
    unsigned r = (u + 0x7fffu + ((u >> 16) & 1u)) >> 16;   // RNE
    return (unsigned short)r;
}
__device__ __forceinline__ float bfl(u32 w) { return __uint_as_float(w << 16); }
__device__ __forceinline__ float bfh(u32 w) { return __uint_as_float(w & 0xffff0000u); }

// ---- zero meta -------------------------------------------------------------
__global__ __launch_bounds__(256) void k_zero(u32* __restrict__ p, int n) {
    int i = blockIdx.x * 256 + threadIdx.x;
    if (i < n) p[i] = 0u;
}

// ---- coarse bucket histogram + fused scan (last block) ---------------------
__global__ __launch_bounds__(256) void k_bhist(const int* __restrict__ cols,
                                               u32* __restrict__ gbh,
                                               u32* __restrict__ done,
                                               u32* __restrict__ bscan,
                                               u32* __restrict__ gcurb,
                                               int E, int NB) {
    __shared__ u32 h[256];
    __shared__ u32 isLast;
    int tid = threadIdx.x;
    h[tid] = 0;
    __syncthreads();
    for (int i = blockIdx.x * 256 + tid; i < E; i += gridDim.x * 256)
        atomicAdd(&h[((u32)cols[i]) >> BSH], 1u);
    __syncthreads();
    if (tid < NB && h[tid]) atomicAdd(&gbh[tid], h[tid]);
    __threadfence();
    if (tid == 0) isLast = (atomicAdd(done, 1u) == gridDim.x - 1) ? 1u : 0u;
    __syncthreads();
    if (isLast) {
        __threadfence();
        u32 v = (tid < NB) ? atomicAdd(&gbh[tid], 0u) : 0u;  // coherent read
        h[tid] = v;
        __syncthreads();
        for (int o = 1; o < 256; o <<= 1) {
            u32 t = (tid >= o) ? h[tid - o] : 0u;
            __syncthreads();
            h[tid] += t;
            __syncthreads();
        }
        u32 excl = h[tid] - v;
        if (tid < NB) { bscan[tid] = excl; gcurb[tid] = excl; }
        if (tid == 0) bscan[NB] = (u32)E;
    }
}

// ---- partition: edges -> part[] grouped by coarse bucket, LDS-reordered ----
// part element packs (col & 511) << 17 | row  (N < 2^17).
__global__ __launch_bounds__(256) void k_part(const int* __restrict__ rows,
                                              const int* __restrict__ cols,
                                              u32* __restrict__ gcurb,
                                              u32* __restrict__ part, int E) {
    __shared__ u32 hist[256];
    __shared__ u32 off[256];
    __shared__ u32 obase[256];
    __shared__ u32 cur[256];
    __shared__ u32 sc[256];
    __shared__ u32 stage[PCHUNK];
    __shared__ unsigned char sbk[PCHUNK];
    const int tid = threadIdx.x;
    const int e0  = blockIdx.x * PCHUNK;
    u32 er[32], ec[32];

    hist[tid] = 0;
    __syncthreads();
#pragma unroll
    for (int j = 0; j < 32; ++j) {
        int e = e0 + j * 256 + tid;
        if (e < E) {
            ec[j] = (u32)cols[e];
            er[j] = (u32)rows[e];
            atomicAdd(&hist[ec[j] >> BSH], 1u);
        } else ec[j] = 0xFFFFFFFFu;
    }
    __syncthreads();
    u32 v = hist[tid];
    sc[tid] = v;
    __syncthreads();
    for (int o = 1; o < 256; o <<= 1) {
        u32 t = (tid >= o) ? sc[tid - o] : 0u;
        __syncthreads();
        sc[tid] += t;
        __syncthreads();
    }
    off[tid] = sc[tid] - v;
    cur[tid] = sc[tid] - v;
    obase[tid] = v ? atomicAdd(&gcurb[tid], v) : 0u;
    __syncthreads();
#pragma unroll
    for (int j = 0; j < 32; ++j) {
        if (ec[j] != 0xFFFFFFFFu) {
            u32 bk  = ec[j] >> BSH;
            u32 pos = atomicAdd(&cur[bk], 1u);
            stage[pos] = ((ec[j] & (BSZ - 1)) << 17) | er[j];
            sbk[pos]   = (unsigned char)bk;
        }
    }
    __syncthreads();
    const int total = (e0 + PCHUNK <= E) ? PCHUNK : (E - e0);
    for (int i = tid; i < total; i += 256) {
        u32 bk = sbk[i];
        part[obase[bk] + ((u32)i - off[bk])] = stage[i];
    }
}

// ---- per-bucket placement + s0 = bf16(dis*x) emission ----------------------
__global__ __launch_bounds__(256) void k_place2(const u32* __restrict__ bscan,
                                                const u32* __restrict__ part,
                                                const float* __restrict__ x,
                                                u32* __restrict__ rowptr,
                                                float* __restrict__ dis,
                                                unsigned short* __restrict__ s0,
                                                int* __restrict__ eidx, int N) {
    __shared__ u32 cnt_[512];
    __shared__ u32 off_[513];
    __shared__ u32 sc[256];
    __shared__ u32 cur[512];
    __shared__ u32 outb[CAP];
    const int tid = threadIdx.x;
    const int b   = blockIdx.x;
    const int n0  = b << BSH;
    const u32 base = bscan[b];
    const u32 cntB = bscan[b + 1] - base;

    cnt_[tid] = 0; cnt_[tid + 256] = 0;
    __syncthreads();
    for (u32 i = tid; i < cntB; i += 256)
        atomicAdd(&cnt_[part[base + i] >> 17], 1u);
    __syncthreads();
    u32 c0 = cnt_[2 * tid], c1 = cnt_[2 * tid + 1];
    u32 s = c0 + c1;
    sc[tid] = s;
    __syncthreads();
    for (int o = 1; o < 256; o <<= 1) {
        u32 t = (tid >= o) ? sc[tid - o] : 0u;
        __syncthreads();
        sc[tid] += t;
        __syncthreads();
    }
    u32 ex = sc[tid] - s;
    off_[2 * tid] = ex;          cur[2 * tid] = ex;
    off_[2 * tid + 1] = ex + c0; cur[2 * tid + 1] = ex + c0;
    if (tid == 0) off_[512] = cntB;
    __syncthreads();
    for (int j = tid; j < 512; j += 256) {
        int n = n0 + j;
        if (n < N) {
            rowptr[n] = base + off_[j];
            dis[n]    = rsqrtf(1.0f + (float)cnt_[j]);
        }
    }
    // emit s0 = bf16(dis * x) for this bucket's nodes (coalesced)
    {
        int nmax = min(512, N - n0);
        for (int idx = tid; idx < nmax * 16; idx += 256) {
            int nl = idx >> 4, f4 = idx & 15;
            float d  = rsqrtf(1.0f + (float)cnt_[nl]);
            float4 v = ((const float4*)(x + (size_t)(n0 + nl) * HF))[f4];
            ushort4 pk;
            pk.x = f2bf(d * v.x); pk.y = f2bf(d * v.y);
            pk.z = f2bf(d * v.z); pk.w = f2bf(d * v.w);
            *(ushort4*)&s0[(size_t)(n0 + nl) * HF + f4 * 4] = pk;
        }
    }
    if (cntB <= CAP) {
        for (u32 i = tid; i < cntB; i += 256) {
            u32 p   = part[base + i];
            u32 pos = atomicAdd(&cur[p >> 17], 1u);
            outb[pos] = p & 0x1FFFFu;
        }
        __syncthreads();
        for (u32 i = tid; i < cntB; i += 256)
            eidx[base + i] = (int)outb[i];
    } else {
        int j0 = 0;
        while (j0 < 512) {
            int j1 = j0 + 1;
            while (j1 < 512 && off_[j1 + 1] - off_[j0] <= CAP) ++j1;
            u32 p0 = off_[j0], p1 = off_[j1];
            for (u32 i = tid; i < cntB; i += 256) {
                u32 p  = part[base + i];
                u32 lc = p >> 17;
                if (lc >= (u32)j0 && lc < (u32)j1) {
                    u32 pos = atomicAdd(&cur[lc], 1u);
                    outb[pos - p0] = p & 0x1FFFFu;
                }
            }
            __syncthreads();
            for (u32 i = tid; i < p1 - p0; i += 256)
                eidx[base + p0 + i] = (int)outb[i];
            __syncthreads();
            j0 = j1;
        }
    }
}

// ---- CSR gather + post-aggregation dense transform -------------------------
// t[n] = Sum_{r in closed nbrs(n)} hs[r]   (hs pre-scaled by dis)
// h[n] = relu( dis[n] * (t[n] @ W) + b )
// OUTSCALE=1: store bf16(dis[n]*h[n])  (next layer's messages)
// OUTSCALE=0: store bf16(h[n])         (pool input)
// One wave per node; 4 quarter-waves each load a full 128B bf16 row.
// W staged transposed in LDS with 17-float4 row pitch (conflict-free b128).
template <int OUTSCALE>
__global__ __launch_bounds__(256) void k_gather(const u32* __restrict__ rowptr,
                                                const int* __restrict__ eidx,
                                                const float* __restrict__ dis,
                                                const u32* __restrict__ hs,   // bf16 pairs
                                                const float* __restrict__ W,  // [k][j] 64x64
                                                const float* __restrict__ bvec,
                                                unsigned short* __restrict__ outbf,
                                                int N, int E) {
    __shared__ float4 wt4[64 * 17];  // wt4[j*17+k4] = {W[4k4..4k4+3][j]}
    const int tid  = threadIdx.x;
    {
        int j = tid & 63;
        for (int k4 = tid >> 6; k4 < 16; k4 += 4) {
            float4 w;
            w.x = W[(4 * k4 + 0) * 64 + j];
            w.y = W[(4 * k4 + 1) * 64 + j];
            w.z = W[(4 * k4 + 2) * 64 + j];
            w.w = W[(4 * k4 + 3) * 64 + j];
            wt4[j * 17 + k4] = w;
        }
    }
    __syncthreads();

    const int wv   = tid >> 6;
    const int lane = tid & 63;
    const int q    = lane >> 4;      // quarter 0..3
    const int f4   = lane & 15;      // feature quad
    const int n    = blockIdx.x * 4 + wv;
    if (n >= N) return;

    u32 start = rowptr[n];
    u32 end   = (n + 1 < N) ? rowptr[n + 1] : (u32)E;
    float dn  = dis[n];
    float4 acc = float4{0.f, 0.f, 0.f, 0.f};

    u32 e = start + q;
    for (; e + 12 < end; e += 16) {          // 4 edges per quarter per iter
        int r0 = eidx[e], r1 = eidx[e + 4], r2 = eidx[e + 8], r3 = eidx[e + 12];
        uint2 w0 = ((const uint2*)(hs + (size_t)r0 * 32))[f4];
        uint2 w1 = ((const uint2*)(hs + (size_t)r1 * 32))[f4];
        uint2 w2 = ((const uint2*)(hs + (size_t)r2 * 32))[f4];
        uint2 w3 = ((const uint2*)(hs + (size_t)r3 * 32))[f4];
        acc.x += (bfl(w0.x) + bfl(w1.x)) + (bfl(w2.x) + bfl(w3.x));
        acc.y += (bfh(w0.x) + bfh(w1.x)) + (bfh(w2.x) + bfh(w3.x));
        acc.z += (bfl(w0.y) + bfl(w1.y)) + (bfl(w2.y) + bfl(w3.y));
        acc.w += (bfh(w0.y) + bfh(w1.y)) + (bfh(w2.y) + bfh(w3.y));
    }
    for (; e < end; e += 4) {
        int r = eidx[e];
        uint2 w = ((const uint2*)(hs + (size_t)r * 32))[f4];
        acc.x += bfl(w.x); acc.y += bfh(w.x);
        acc.z += bfl(w.y); acc.w += bfh(w.y);
    }
    if (q == 0) {                            // self-loop
        uint2 w = ((const uint2*)(hs + (size_t)n * 32))[f4];
        acc.x += bfl(w.x); acc.y += bfh(w.x);
        acc.z += bfl(w.y); acc.w += bfh(w.y);
    }
    // quarter reduce: lane L ends with t[4*(L&15) .. +3]
    acc.x += __shfl_xor(acc.x, 32); acc.y += __shfl_xor(acc.y, 32);
    acc.z += __shfl_xor(acc.z, 32); acc.w += __shfl_xor(acc.w, 32);
    acc.x += __shfl_xor(acc.x, 16); acc.y += __shfl_xor(acc.y, 16);
    acc.z += __shfl_xor(acc.z, 16); acc.w += __shfl_xor(acc.w, 16);

    // matvec: out[j] = Sum_k t[k] * W[k][j]; lane j computes feature j.
    // t quad 4k4.. lives in lane k4 (readlane broadcast, no LDS round-trip).
    float o = 0.f;
#pragma unroll
    for (int k4 = 0; k4 < 16; ++k4) {
        float tx = __shfl(acc.x, k4);
        float ty = __shfl(acc.y, k4);
        float tz = __shfl(acc.z, k4);
        float tw = __shfl(acc.w, k4);
        float4 w4 = wt4[lane * 17 + k4];
        o += tx * w4.x + ty * w4.y + tz * w4.z + tw * w4.w;
    }
    float h = fmaxf(dn * o + bvec[lane], 0.f);
    outbf[(size_t)n * HF + lane] = f2bf(OUTSCALE ? dn * h : h);
}

// ---- fused mean-pool + MLP head: one block per graph -----------------------
__device__ __forceinline__ int lower_bound(const int* __restrict__ a, int n, int key) {
    int lo = 0, hi = n;
    while (lo < hi) { int mid = (lo + hi) >> 1; if (a[mid] < key) lo = mid + 1; else hi = mid; }
    return lo;
}

__global__ __launch_bounds__(256) void k_poolhead(const u32* __restrict__ h2,  // bf16 pairs (relu'd)
                                                  const int* __restrict__ batch,
                                                  const float* __restrict__ Wl1,
                                                  const float* __restrict__ bl1,
                                                  const float* __restrict__ Wl2,
                                                  const float* __restrict__ bl2,
                                                  float* __restrict__ out, int N) {
    __shared__ float red[4][64];
    __shared__ float gm[64];
    const int g    = blockIdx.x;
    const int lane = threadIdx.x & 63;
    const int w    = threadIdx.x >> 6;
    int s = lower_bound(batch, N, g);
    int e = lower_bound(batch, N, g + 1);
    float acc = 0.f;
    for (int n = s + w; n < e; n += 4) {
        u32 wv = h2[(size_t)n * 32 + (lane >> 1)];
        acc += (lane & 1) ? bfh(wv) : bfl(wv);
    }
    red[w][lane] = acc;
    __syncthreads();
    if (w == 0) {
        float t = red[0][lane] + red[1][lane] + red[2][lane] + red[3][lane];
        gm[lane] = t / fmaxf((float)(e - s), 1.0f);
    }
    __syncthreads();
    if (w == 0 && lane < 32) {
        float a = bl1[lane];
#pragma unroll
        for (int k = 0; k < 64; ++k) a += gm[k] * Wl1[k * 32 + lane];
        a = fmaxf(a, 0.f);
        float l0 = a * Wl2[2 * lane];
        float l1 = a * Wl2[2 * lane + 1];
#pragma unroll
        for (int o = 1; o < 32; o <<= 1) {
            l0 += __shfl_xor(l0, o);
            l1 += __shfl_xor(l1, o);
        }
        if (lane == 0) {
            l0 += bl2[0]; l1 += bl2[1];
            float m   = fmaxf(l0, l1);
            float lse = m + logf(expf(l0 - m) + expf(l1 - m));
            out[2 * g]     = l0 - lse;
            out[2 * g + 1] = l1 - lse;
        }
    }
}

// ---- driver ----------------------------------------------------------------
extern "C" void kernel_launch(void* const* d_in, const int* in_sizes, int n_in,
                              void* d_out, int out_size, void* d_ws, size_t ws_size,
                              hipStream_t stream) {
    const float* x   = (const float*)d_in[0];
    const int*   ei  = (const int*)d_in[1];
    const int*   bi  = (const int*)d_in[2];
    const float* W1  = (const float*)d_in[3];
    const float* b1  = (const float*)d_in[4];
    const float* W2  = (const float*)d_in[5];
    const float* b2  = (const float*)d_in[6];
    const float* Wl1 = (const float*)d_in[7];
    const float* bl1 = (const float*)d_in[8];
    const float* Wl2 = (const float*)d_in[9];
    const float* bl2 = (const float*)d_in[10];
    float* out = (float*)d_out;

    const int N = in_sizes[0] / HF;
    const int E = in_sizes[1] / 2;
    const int* rows = ei;
    const int* cols = ei + E;
    const int NB = (N + BSZ - 1) / BSZ;

    // workspace (4B units).
    //   s0  (bf16 NxHF): written by place2, read by gather1; h2 aliases it.
    //   s1  (bf16 NxHF): written by gather1, read by gather2; part aliases it
    //       (part dead after place2, s1 written after).
    float* ws = (float*)d_ws;
    size_t o = 0;
    float* dis    = ws + o; o += ((size_t)N + 63) / 64 * 64;
    unsigned short* s0 = (unsigned short*)(ws + o); o += (size_t)N * 32;
    size_t s1sz = (size_t)N * 32 > (size_t)E ? (size_t)N * 32 : (size_t)E;
    unsigned short* s1 = (unsigned short*)(ws + o); o += s1sz;
    u32*   part   = (u32*)s1;
    unsigned short* h2 = s0;
    u32*   rowptr = (u32*)(ws + o); o += ((size_t)N + 63) / 64 * 64;
    int*   eidx   = (int*)(ws + o); o += (size_t)E;
    u32*   gbh    = (u32*)(ws + o); o += 256;
    u32*   done   = (u32*)(ws + o); o += 64;
    u32*   bscan  = (u32*)(ws + o); o += 320;
    u32*   gcurb  = (u32*)(ws + o); o += 256;

    // CSR build
    k_zero<<<2, 256, 0, stream>>>(gbh, 256 + 64);             // gbh + done
    k_bhist<<<256, 256, 0, stream>>>(cols, gbh, done, bscan, gcurb, E, NB);
    k_part<<<(E + PCHUNK - 1) / PCHUNK, 256, 0, stream>>>(rows, cols, gcurb, part, E);
    k_place2<<<NB, 256, 0, stream>>>(bscan, part, x, rowptr, dis, s0, eidx, N);

    // layer 1: s1 = bf16( dis * relu( dis*(gather(s0) @ W1) + b1 ) )
    k_gather<1><<<(N + 3) / 4, 256, 0, stream>>>(rowptr, eidx, dis, (const u32*)s0,
                                                 W1, b1, s1, N, E);
    // layer 2: h2 = bf16( relu( dis*(gather(s1) @ W2) + b2 ) )
    k_gather<0><<<(N + 3) / 4, 256, 0, stream>>>(rowptr, eidx, dis, (const u32*)s1,
                                                 W2, b2, h2, N, E);

    // mean pool + head
    k_poolhead<<<256, 256, 0, stream>>>((const u32*)h2, bi, Wl1, bl1, Wl2, bl2, out, N);
}

// Round 8
// 411.919 us; speedup vs baseline: 1.0439x; 1.0439x over previous
//
#include <hip/hip_runtime.h>
#include <cstdint>
#include <cstddef>

// GCN: h1 = relu(Â (x W1) + b1); h2 = relu(Â (h1 W2) + b2);
// g = mean-pool(h2 by batch); out = log_softmax(relu(g Wl1 + bl1) Wl2 + bl2)
// Â = D^-1/2 (A + I) D^-1/2.
//
// R8: distributivity kept ( Â(xW) = (Âx)W ) but the per-node transform runs
// in a standalone LDS-tiled kernel (64x weight reuse) — R5/R7 proved in-gather
// matvecs are a 2x loss. Gather is the pure-sum R6 form (no LDS, no epilogue
// math). Pipeline: place2 emits s0=bf16(dis*x); gather1 sums -> t1;
// trans1: h1s=bf16(dis*relu(dis*(t1@W1)+b1)); gather2 sums -> t2;
// trans2: h2=bf16(relu(dis*(t2@W2)+b2)); poolhead. 9 dispatches.

#define HF 64          // feature width
#define BSH 9          // bucket shift: 512 nodes per bucket
#define BSZ 512
#define PCHUNK 8192    // edges per k_part block
#define CAP 12288      // LDS out capacity in k_place2

typedef unsigned u32;

__device__ __forceinline__ unsigned short f2bf(float x) {
    unsigned u = __float_as_uint(x);
    unsigned r = (u + 0x7fffu + ((u >> 16) & 1u)) >> 16;   // RNE
    return (unsigned short)r;
}
__device__ __forceinline__ float bfl(u32 w) { return __uint_as_float(w << 16); }
__device__ __forceinline__ float bfh(u32 w) { return __uint_as_float(w & 0xffff0000u); }
__device__ __forceinline__ float bf2f(unsigned short s) { return __uint_as_float(((u32)s) << 16); }

// ---- zero meta -------------------------------------------------------------
__global__ __launch_bounds__(256) void k_zero(u32* __restrict__ p, int n) {
    int i = blockIdx.x * 256 + threadIdx.x;
    if (i < n) p[i] = 0u;
}

// ---- coarse bucket histogram + fused scan (last block) ---------------------
__global__ __launch_bounds__(256) void k_bhist(const int* __restrict__ cols,
                                               u32* __restrict__ gbh,
                                               u32* __restrict__ done,
                                               u32* __restrict__ bscan,
                                               u32* __restrict__ gcurb,
                                               int E, int NB) {
    __shared__ u32 h[256];
    __shared__ u32 isLast;
    int tid = threadIdx.x;
    h[tid] = 0;
    __syncthreads();
    for (int i = blockIdx.x * 256 + tid; i < E; i += gridDim.x * 256)
        atomicAdd(&h[((u32)cols[i]) >> BSH], 1u);
    __syncthreads();
    if (tid < NB && h[tid]) atomicAdd(&gbh[tid], h[tid]);
    __threadfence();
    if (tid == 0) isLast = (atomicAdd(done, 1u) == gridDim.x - 1) ? 1u : 0u;
    __syncthreads();
    if (isLast) {
        __threadfence();
        u32 v = (tid < NB) ? atomicAdd(&gbh[tid], 0u) : 0u;  // coherent read
        h[tid] = v;
        __syncthreads();
        for (int o = 1; o < 256; o <<= 1) {
            u32 t = (tid >= o) ? h[tid - o] : 0u;
            __syncthreads();
            h[tid] += t;
            __syncthreads();
        }
        u32 excl = h[tid] - v;
        if (tid < NB) { bscan[tid] = excl; gcurb[tid] = excl; }
        if (tid == 0) bscan[NB] = (u32)E;
    }
}

// ---- partition: edges -> part[] grouped by coarse bucket, LDS-reordered ----
// part element packs (col & 511) << 17 | row  (N < 2^17).
__global__ __launch_bounds__(256) void k_part(const int* __restrict__ rows,
                                              const int* __restrict__ cols,
                                              u32* __restrict__ gcurb,
                                              u32* __restrict__ part, int E) {
    __shared__ u32 hist[256];
    __shared__ u32 off[256];
    __shared__ u32 obase[256];
    __shared__ u32 cur[256];
    __shared__ u32 sc[256];
    __shared__ u32 stage[PCHUNK];
    __shared__ unsigned char sbk[PCHUNK];
    const int tid = threadIdx.x;
    const int e0  = blockIdx.x * PCHUNK;
    u32 er[32], ec[32];

    hist[tid] = 0;
    __syncthreads();
#pragma unroll
    for (int j = 0; j < 32; ++j) {
        int e = e0 + j * 256 + tid;
        if (e < E) {
            ec[j] = (u32)cols[e];
            er[j] = (u32)rows[e];
            atomicAdd(&hist[ec[j] >> BSH], 1u);
        } else ec[j] = 0xFFFFFFFFu;
    }
    __syncthreads();
    u32 v = hist[tid];
    sc[tid] = v;
    __syncthreads();
    for (int o = 1; o < 256; o <<= 1) {
        u32 t = (tid >= o) ? sc[tid - o] : 0u;
        __syncthreads();
        sc[tid] += t;
        __syncthreads();
    }
    off[tid] = sc[tid] - v;
    cur[tid] = sc[tid] - v;
    obase[tid] = v ? atomicAdd(&gcurb[tid], v) : 0u;
    __syncthreads();
#pragma unroll
    for (int j = 0; j < 32; ++j) {
        if (ec[j] != 0xFFFFFFFFu) {
            u32 bk  = ec[j] >> BSH;
            u32 pos = atomicAdd(&cur[bk], 1u);
            stage[pos] = ((ec[j] & (BSZ - 1)) << 17) | er[j];
            sbk[pos]   = (unsigned char)bk;
        }
    }
    __syncthreads();
    const int total = (e0 + PCHUNK <= E) ? PCHUNK : (E - e0);
    for (int i = tid; i < total; i += 256) {
        u32 bk = sbk[i];
        part[obase[bk] + ((u32)i - off[bk])] = stage[i];
    }
}

// ---- per-bucket placement + s0 = bf16(dis*x) emission ----------------------
__global__ __launch_bounds__(256) void k_place2(const u32* __restrict__ bscan,
                                                const u32* __restrict__ part,
                                                const float* __restrict__ x,
                                                u32* __restrict__ rowptr,
                                                float* __restrict__ dis,
                                                unsigned short* __restrict__ s0,
                                                int* __restrict__ eidx, int N) {
    __shared__ u32 cnt_[512];
    __shared__ u32 off_[513];
    __shared__ u32 sc[256];
    __shared__ u32 cur[512];
    __shared__ u32 outb[CAP];
    const int tid = threadIdx.x;
    const int b   = blockIdx.x;
    const int n0  = b << BSH;
    const u32 base = bscan[b];
    const u32 cntB = bscan[b + 1] - base;

    cnt_[tid] = 0; cnt_[tid + 256] = 0;
    __syncthreads();
    for (u32 i = tid; i < cntB; i += 256)
        atomicAdd(&cnt_[part[base + i] >> 17], 1u);
    __syncthreads();
    u32 c0 = cnt_[2 * tid], c1 = cnt_[2 * tid + 1];
    u32 s = c0 + c1;
    sc[tid] = s;
    __syncthreads();
    for (int o = 1; o < 256; o <<= 1) {
        u32 t = (tid >= o) ? sc[tid - o] : 0u;
        __syncthreads();
        sc[tid] += t;
        __syncthreads();
    }
    u32 ex = sc[tid] - s;
    off_[2 * tid] = ex;          cur[2 * tid] = ex;
    off_[2 * tid + 1] = ex + c0; cur[2 * tid + 1] = ex + c0;
    if (tid == 0) off_[512] = cntB;
    __syncthreads();
    for (int j = tid; j < 512; j += 256) {
        int n = n0 + j;
        if (n < N) {
            rowptr[n] = base + off_[j];
            dis[n]    = rsqrtf(1.0f + (float)cnt_[j]);
        }
    }
    // emit s0 = bf16(dis * x) for this bucket's nodes (coalesced)
    {
        int nmax = min(512, N - n0);
        for (int idx = tid; idx < nmax * 16; idx += 256) {
            int nl = idx >> 4, f4 = idx & 15;
            float d  = rsqrtf(1.0f + (float)cnt_[nl]);
            float4 v = ((const float4*)(x + (size_t)(n0 + nl) * HF))[f4];
            ushort4 pk;
            pk.x = f2bf(d * v.x); pk.y = f2bf(d * v.y);
            pk.z = f2bf(d * v.z); pk.w = f2bf(d * v.w);
            *(ushort4*)&s0[(size_t)(n0 + nl) * HF + f4 * 4] = pk;
        }
    }
    if (cntB <= CAP) {
        for (u32 i = tid; i < cntB; i += 256) {
            u32 p   = part[base + i];
            u32 pos = atomicAdd(&cur[p >> 17], 1u);
            outb[pos] = p & 0x1FFFFu;
        }
        __syncthreads();
        for (u32 i = tid; i < cntB; i += 256)
            eidx[base + i] = (int)outb[i];
    } else {
        int j0 = 0;
        while (j0 < 512) {
            int j1 = j0 + 1;
            while (j1 < 512 && off_[j1 + 1] - off_[j0] <= CAP) ++j1;
            u32 p0 = off_[j0], p1 = off_[j1];
            for (u32 i = tid; i < cntB; i += 256) {
                u32 p  = part[base + i];
                u32 lc = p >> 17;
                if (lc >= (u32)j0 && lc < (u32)j1) {
                    u32 pos = atomicAdd(&cur[lc], 1u);
                    outb[pos - p0] = p & 0x1FFFFu;
                }
            }
            __syncthreads();
            for (u32 i = tid; i < p1 - p0; i += 256)
                eidx[base + p0 + i] = (int)outb[i];
            __syncthreads();
            j0 = j1;
        }
    }
}

// ---- CSR gather: pure closed-neighborhood sum, bf16 in / bf16 out ----------
// t[n] = Sum_{r in nbrs(n) + self} hs[r]. No dis/bias/relu here (k_trans does
// that with 64x LDS reuse — in-gather matvecs measured 2x slower, R5/R7).
// One wave per node; 4 quarter-waves each load a full 128B bf16 row.
__global__ __launch_bounds__(256) void k_gather(const u32* __restrict__ rowptr,
                                                const int* __restrict__ eidx,
                                                const u32* __restrict__ hs,   // bf16 pairs
                                                unsigned short* __restrict__ outbf,
                                                int N, int E) {
    const int tid  = threadIdx.x;
    const int wv   = tid >> 6;
    const int lane = tid & 63;
    const int q    = lane >> 4;      // quarter 0..3
    const int f4   = lane & 15;      // feature quad
    const int n    = blockIdx.x * 4 + wv;
    if (n >= N) return;

    u32 start = rowptr[n];
    u32 end   = (n + 1 < N) ? rowptr[n + 1] : (u32)E;
    float4 acc = float4{0.f, 0.f, 0.f, 0.f};

    u32 e = start + q;
    for (; e + 12 < end; e += 16) {          // 4 edges per quarter per iter
        int r0 = eidx[e], r1 = eidx[e + 4], r2 = eidx[e + 8], r3 = eidx[e + 12];
        uint2 w0 = ((const uint2*)(hs + (size_t)r0 * 32))[f4];
        uint2 w1 = ((const uint2*)(hs + (size_t)r1 * 32))[f4];
        uint2 w2 = ((const uint2*)(hs + (size_t)r2 * 32))[f4];
        uint2 w3 = ((const uint2*)(hs + (size_t)r3 * 32))[f4];
        acc.x += (bfl(w0.x) + bfl(w1.x)) + (bfl(w2.x) + bfl(w3.x));
        acc.y += (bfh(w0.x) + bfh(w1.x)) + (bfh(w2.x) + bfh(w3.x));
        acc.z += (bfl(w0.y) + bfl(w1.y)) + (bfl(w2.y) + bfl(w3.y));
        acc.w += (bfh(w0.y) + bfh(w1.y)) + (bfh(w2.y) + bfh(w3.y));
    }
    for (; e < end; e += 4) {
        int r = eidx[e];
        uint2 w = ((const uint2*)(hs + (size_t)r * 32))[f4];
        acc.x += bfl(w.x); acc.y += bfh(w.x);
        acc.z += bfl(w.y); acc.w += bfh(w.y);
    }
    if (q == 0) {                            // self-loop
        uint2 w = ((const uint2*)(hs + (size_t)n * 32))[f4];
        acc.x += bfl(w.x); acc.y += bfh(w.x);
        acc.z += bfl(w.y); acc.w += bfh(w.y);
    }
    acc.x += __shfl_xor(acc.x, 32); acc.y += __shfl_xor(acc.y, 32);
    acc.z += __shfl_xor(acc.z, 32); acc.w += __shfl_xor(acc.w, 32);
    acc.x += __shfl_xor(acc.x, 16); acc.y += __shfl_xor(acc.y, 16);
    acc.z += __shfl_xor(acc.z, 16); acc.w += __shfl_xor(acc.w, 16);

    if (q == 0) {
        ushort4 pk;
        pk.x = f2bf(acc.x); pk.y = f2bf(acc.y);
        pk.z = f2bf(acc.z); pk.w = f2bf(acc.w);
        *(ushort4*)&outbf[(size_t)n * HF + f4 * 4] = pk;
    }
}

// ---- tiled transform: OUT = post( dis[n]*(T[N,64] @ W[64,64]) + b ) --------
// OUTSCALE=1: out = bf16( dis * relu(...) )   (pre-scaled messages)
// OUTSCALE=0: out = bf16( relu(...) )         (pool input)
template <int OUTSCALE>
__global__ __launch_bounds__(256) void k_trans(const unsigned short* __restrict__ T,
                                               const float* __restrict__ W,
                                               const float* __restrict__ dis,
                                               const float* __restrict__ bias,
                                               unsigned short* __restrict__ OUT, int N) {
    __shared__ float ws[64 * 64];
    __shared__ float xs[64 * 68];
    const int tid  = threadIdx.x;
    const int row0 = blockIdx.x * 64;

#pragma unroll
    for (int i = 0; i < 4; ++i) {
        int idx4 = i * 256 + tid;
        *(float4*)&ws[idx4 * 4] = ((const float4*)W)[idx4];
    }
#pragma unroll
    for (int i = 0; i < 4; ++i) {
        int idx4 = i * 256 + tid;
        int r    = idx4 >> 4;
        int kk   = (idx4 & 15) << 2;
        float4 v = float4{0.f, 0.f, 0.f, 0.f};
        int row  = row0 + r;
        if (row < N) {
            ushort4 pk = ((const ushort4*)(T + (size_t)row * HF))[idx4 & 15];
            v.x = bf2f(pk.x); v.y = bf2f(pk.y);
            v.z = bf2f(pk.z); v.w = bf2f(pk.w);
        }
        *(float4*)&xs[r * 68 + kk] = v;
    }
    __syncthreads();

    const int rg = tid >> 4;
    const int cg = tid & 15;
    float4 a0 = float4{0.f, 0.f, 0.f, 0.f};
    float4 a1 = a0, a2 = a0, a3 = a0;

#pragma unroll
    for (int k = 0; k < 64; ++k) {
        float4 wv = *(float4*)&ws[k * 64 + cg * 4];
        float  x0 = xs[(rg * 4 + 0) * 68 + k];
        float  x1 = xs[(rg * 4 + 1) * 68 + k];
        float  x2 = xs[(rg * 4 + 2) * 68 + k];
        float  x3 = xs[(rg * 4 + 3) * 68 + k];
        a0.x += x0 * wv.x; a0.y += x0 * wv.y; a0.z += x0 * wv.z; a0.w += x0 * wv.w;
        a1.x += x1 * wv.x; a1.y += x1 * wv.y; a1.z += x1 * wv.z; a1.w += x1 * wv.w;
        a2.x += x2 * wv.x; a2.y += x2 * wv.y; a2.z += x2 * wv.z; a2.w += x2 * wv.w;
        a3.x += x3 * wv.x; a3.y += x3 * wv.y; a3.z += x3 * wv.z; a3.w += x3 * wv.w;
    }

    float4 bv = ((const float4*)bias)[cg];
    float4 accs[4] = {a0, a1, a2, a3};
#pragma unroll
    for (int j = 0; j < 4; ++j) {
        int row = row0 + rg * 4 + j;
        if (row < N) {
            float d = dis[row];
            float4 a = accs[j];
            a.x = fmaxf(d * a.x + bv.x, 0.f);
            a.y = fmaxf(d * a.y + bv.y, 0.f);
            a.z = fmaxf(d * a.z + bv.z, 0.f);
            a.w = fmaxf(d * a.w + bv.w, 0.f);
            float sc = OUTSCALE ? d : 1.0f;
            ushort4 pk;
            pk.x = f2bf(sc * a.x); pk.y = f2bf(sc * a.y);
            pk.z = f2bf(sc * a.z); pk.w = f2bf(sc * a.w);
            *(ushort4*)&OUT[(size_t)row * HF + cg * 4] = pk;
        }
    }
}

// ---- fused mean-pool + MLP head: one block per graph -----------------------
__device__ __forceinline__ int lower_bound(const int* __restrict__ a, int n, int key) {
    int lo = 0, hi = n;
    while (lo < hi) { int mid = (lo + hi) >> 1; if (a[mid] < key) lo = mid + 1; else hi = mid; }
    return lo;
}

__global__ __launch_bounds__(256) void k_poolhead(const u32* __restrict__ h2,  // bf16 pairs
                                                  const int* __restrict__ batch,
                                                  const float* __restrict__ Wl1,
                                                  const float* __restrict__ bl1,
                                                  const float* __restrict__ Wl2,
                                                  const float* __restrict__ bl2,
                                                  float* __restrict__ out, int N) {
    __shared__ float red[4][64];
    __shared__ float gm[64];
    const int g    = blockIdx.x;
    const int lane = threadIdx.x & 63;
    const int w    = threadIdx.x >> 6;
    int s = lower_bound(batch, N, g);
    int e = lower_bound(batch, N, g + 1);
    float acc = 0.f;
    for (int n = s + w; n < e; n += 4) {
        u32 wv = h2[(size_t)n * 32 + (lane >> 1)];
        acc += (lane & 1) ? bfh(wv) : bfl(wv);
    }
    red[w][lane] = acc;
    __syncthreads();
    if (w == 0) {
        float t = red[0][lane] + red[1][lane] + red[2][lane] + red[3][lane];
        gm[lane] = t / fmaxf((float)(e - s), 1.0f);
    }
    __syncthreads();
    if (w == 0 && lane < 32) {
        float a = bl1[lane];
#pragma unroll
        for (int k = 0; k < 64; ++k) a += gm[k] * Wl1[k * 32 + lane];
        a = fmaxf(a, 0.f);
        float l0 = a * Wl2[2 * lane];
        float l1 = a * Wl2[2 * lane + 1];
#pragma unroll
        for (int o = 1; o < 32; o <<= 1) {
            l0 += __shfl_xor(l0, o);
            l1 += __shfl_xor(l1, o);
        }
        if (lane == 0) {
            l0 += bl2[0]; l1 += bl2[1];
            float m   = fmaxf(l0, l1);
            float lse = m + logf(expf(l0 - m) + expf(l1 - m));
            out[2 * g]     = l0 - lse;
            out[2 * g + 1] = l1 - lse;
        }
    }
}

// ---- driver ----------------------------------------------------------------
extern "C" void kernel_launch(void* const* d_in, const int* in_sizes, int n_in,
                              void* d_out, int out_size, void* d_ws, size_t ws_size,
                              hipStream_t stream) {
    const float* x   = (const float*)d_in[0];
    const int*   ei  = (const int*)d_in[1];
    const int*   bi  = (const int*)d_in[2];
    const float* W1  = (const float*)d_in[3];
    const float* b1  = (const float*)d_in[4];
    const float* W2  = (const float*)d_in[5];
    const float* b2  = (const float*)d_in[6];
    const float* Wl1 = (const float*)d_in[7];
    const float* bl1 = (const float*)d_in[8];
    const float* Wl2 = (const float*)d_in[9];
    const float* bl2 = (const float*)d_in[10];
    float* out = (float*)d_out;

    const int N = in_sizes[0] / HF;
    const int E = in_sizes[1] / 2;
    const int* rows = ei;
    const int* cols = ei + E;
    const int NB = (N + BSZ - 1) / BSZ;

    // workspace (4B units). Two bf16 N x 64 regions:
    //   RA: s0 (place2 out, gather1 in) -> h1s (trans1 out, gather2 in)
    //       -> h2 (trans2 out, poolhead in)
    //   RB: part (dead after place2) -> t1 (gather1 out, trans1 in)
    //       -> t2 (gather2 out, trans2 in)
    float* ws = (float*)d_ws;
    size_t o = 0;
    float* dis    = ws + o; o += ((size_t)N + 63) / 64 * 64;
    unsigned short* RA = (unsigned short*)(ws + o); o += (size_t)N * 32;
    unsigned short* RB = (unsigned short*)(ws + o); o += (size_t)N * 32;  // >= E u32s
    u32*   part   = (u32*)RB;
    u32*   rowptr = (u32*)(ws + o); o += ((size_t)N + 63) / 64 * 64;
    int*   eidx   = (int*)(ws + o); o += (size_t)E;
    u32*   gbh    = (u32*)(ws + o); o += 256;
    u32*   done   = (u32*)(ws + o); o += 64;
    u32*   bscan  = (u32*)(ws + o); o += 320;
    u32*   gcurb  = (u32*)(ws + o); o += 256;

    const int tb = (N + 63) / 64;

    // CSR build (+ s0 emission inside place2)
    k_zero<<<2, 256, 0, stream>>>(gbh, 256 + 64);             // gbh + done
    k_bhist<<<256, 256, 0, stream>>>(cols, gbh, done, bscan, gcurb, E, NB);
    k_part<<<(E + PCHUNK - 1) / PCHUNK, 256, 0, stream>>>(rows, cols, gcurb, part, E);
    k_place2<<<NB, 256, 0, stream>>>(bscan, part, x, rowptr, dis, RA, eidx, N);

    // layer 1: t1 = sum(s0); h1s = bf16( dis * relu( dis*(t1@W1) + b1 ) )
    k_gather<<<(N + 3) / 4, 256, 0, stream>>>(rowptr, eidx, (const u32*)RA, RB, N, E);
    k_trans<1><<<tb, 256, 0, stream>>>(RB, W1, dis, b1, RA, N);
    // layer 2: t2 = sum(h1s); h2 = bf16( relu( dis*(t2@W2) + b2 ) )
    k_gather<<<(N + 3) / 4, 256, 0, stream>>>(rowptr, eidx, (const u32*)RA, RB, N, E);
    k_trans<0><<<tb, 256, 0, stream>>>(RB, W2, dis, b2, RA, N);

    // mean pool + head
    k_poolhead<<<256, 256, 0, stream>>>((const u32*)RA, bi, Wl1, bl1, Wl2, bl2, out, N);
}

// Round 9
// 345.340 us; speedup vs baseline: 1.2452x; 1.1928x over previous
//
#include <hip/hip_runtime.h>
#include <cstdint>
#include <cstddef>

// GCN: h1 = relu(Â (x W1) + b1); h2 = relu(Â (h1 W2) + b2);
// g = mean-pool(h2 by batch); out = log_softmax(relu(g Wl1 + bl1) Wl2 + bl2)
// Â = D^-1/2 (A + I) D^-1/2.
//
// R9: R8 profiling exposed k_trans at 256 VGPRs / 8.4% occupancy / 57.5us
// (full 64-iter unroll hoisted LDS loads and blew the RF; roofline is ~6us).
// Fix: __launch_bounds__(256,4) caps VGPRs at 128 (>=16 waves/CU) and
// partial unroll (8) bounds in-flight ds_read_b128. Everything else is R8's
// proven pipeline: pure-sum gathers + tiled transform + fused build/poolhead.

#define HF 64          // feature width
#define BSH 9          // bucket shift: 512 nodes per bucket
#define BSZ 512
#define PCHUNK 8192    // edges per k_part block
#define CAP 12288      // LDS out capacity in k_place2

typedef unsigned u32;

__device__ __forceinline__ unsigned short f2bf(float x) {
    unsigned u = __float_as_uint(x);
    unsigned r = (u + 0x7fffu + ((u >> 16) & 1u)) >> 16;   // RNE
    return (unsigned short)r;
}
__device__ __forceinline__ float bfl(u32 w) { return __uint_as_float(w << 16); }
__device__ __forceinline__ float bfh(u32 w) { return __uint_as_float(w & 0xffff0000u); }
__device__ __forceinline__ float bf2f(unsigned short s) { return __uint_as_float(((u32)s) << 16); }

// ---- zero meta -------------------------------------------------------------
__global__ __launch_bounds__(256) void k_zero(u32* __restrict__ p, int n) {
    int i = blockIdx.x * 256 + threadIdx.x;
    if (i < n) p[i] = 0u;
}

// ---- coarse bucket histogram + fused scan (last block) ---------------------
__global__ __launch_bounds__(256) void k_bhist(const int* __restrict__ cols,
                                               u32* __restrict__ gbh,
                                               u32* __restrict__ done,
                                               u32* __restrict__ bscan,
                                               u32* __restrict__ gcurb,
                                               int E, int NB) {
    __shared__ u32 h[256];
    __shared__ u32 isLast;
    int tid = threadIdx.x;
    h[tid] = 0;
    __syncthreads();
    for (int i = blockIdx.x * 256 + tid; i < E; i += gridDim.x * 256)
        atomicAdd(&h[((u32)cols[i]) >> BSH], 1u);
    __syncthreads();
    if (tid < NB && h[tid]) atomicAdd(&gbh[tid], h[tid]);
    __threadfence();
    if (tid == 0) isLast = (atomicAdd(done, 1u) == gridDim.x - 1) ? 1u : 0u;
    __syncthreads();
    if (isLast) {
        __threadfence();
        u32 v = (tid < NB) ? atomicAdd(&gbh[tid], 0u) : 0u;  // coherent read
        h[tid] = v;
        __syncthreads();
        for (int o = 1; o < 256; o <<= 1) {
            u32 t = (tid >= o) ? h[tid - o] : 0u;
            __syncthreads();
            h[tid] += t;
            __syncthreads();
        }
        u32 excl = h[tid] - v;
        if (tid < NB) { bscan[tid] = excl; gcurb[tid] = excl; }
        if (tid == 0) bscan[NB] = (u32)E;
    }
}

// ---- partition: edges -> part[] grouped by coarse bucket, LDS-reordered ----
// part element packs (col & 511) << 17 | row  (N < 2^17).
__global__ __launch_bounds__(256) void k_part(const int* __restrict__ rows,
                                              const int* __restrict__ cols,
                                              u32* __restrict__ gcurb,
                                              u32* __restrict__ part, int E) {
    __shared__ u32 hist[256];
    __shared__ u32 off[256];
    __shared__ u32 obase[256];
    __shared__ u32 cur[256];
    __shared__ u32 sc[256];
    __shared__ u32 stage[PCHUNK];
    __shared__ unsigned char sbk[PCHUNK];
    const int tid = threadIdx.x;
    const int e0  = blockIdx.x * PCHUNK;
    u32 er[32], ec[32];

    hist[tid] = 0;
    __syncthreads();
#pragma unroll
    for (int j = 0; j < 32; ++j) {
        int e = e0 + j * 256 + tid;
        if (e < E) {
            ec[j] = (u32)cols[e];
            er[j] = (u32)rows[e];
            atomicAdd(&hist[ec[j] >> BSH], 1u);
        } else ec[j] = 0xFFFFFFFFu;
    }
    __syncthreads();
    u32 v = hist[tid];
    sc[tid] = v;
    __syncthreads();
    for (int o = 1; o < 256; o <<= 1) {
        u32 t = (tid >= o) ? sc[tid - o] : 0u;
        __syncthreads();
        sc[tid] += t;
        __syncthreads();
    }
    off[tid] = sc[tid] - v;
    cur[tid] = sc[tid] - v;
    obase[tid] = v ? atomicAdd(&gcurb[tid], v) : 0u;
    __syncthreads();
#pragma unroll
    for (int j = 0; j < 32; ++j) {
        if (ec[j] != 0xFFFFFFFFu) {
            u32 bk  = ec[j] >> BSH;
            u32 pos = atomicAdd(&cur[bk], 1u);
            stage[pos] = ((ec[j] & (BSZ - 1)) << 17) | er[j];
            sbk[pos]   = (unsigned char)bk;
        }
    }
    __syncthreads();
    const int total = (e0 + PCHUNK <= E) ? PCHUNK : (E - e0);
    for (int i = tid; i < total; i += 256) {
        u32 bk = sbk[i];
        part[obase[bk] + ((u32)i - off[bk])] = stage[i];
    }
}

// ---- per-bucket placement + s0 = bf16(dis*x) emission ----------------------
__global__ __launch_bounds__(256) void k_place2(const u32* __restrict__ bscan,
                                                const u32* __restrict__ part,
                                                const float* __restrict__ x,
                                                u32* __restrict__ rowptr,
                                                float* __restrict__ dis,
                                                unsigned short* __restrict__ s0,
                                                int* __restrict__ eidx, int N) {
    __shared__ u32 cnt_[512];
    __shared__ u32 off_[513];
    __shared__ u32 sc[256];
    __shared__ u32 cur[512];
    __shared__ u32 outb[CAP];
    const int tid = threadIdx.x;
    const int b   = blockIdx.x;
    const int n0  = b << BSH;
    const u32 base = bscan[b];
    const u32 cntB = bscan[b + 1] - base;

    cnt_[tid] = 0; cnt_[tid + 256] = 0;
    __syncthreads();
    for (u32 i = tid; i < cntB; i += 256)
        atomicAdd(&cnt_[part[base + i] >> 17], 1u);
    __syncthreads();
    u32 c0 = cnt_[2 * tid], c1 = cnt_[2 * tid + 1];
    u32 s = c0 + c1;
    sc[tid] = s;
    __syncthreads();
    for (int o = 1; o < 256; o <<= 1) {
        u32 t = (tid >= o) ? sc[tid - o] : 0u;
        __syncthreads();
        sc[tid] += t;
        __syncthreads();
    }
    u32 ex = sc[tid] - s;
    off_[2 * tid] = ex;          cur[2 * tid] = ex;
    off_[2 * tid + 1] = ex + c0; cur[2 * tid + 1] = ex + c0;
    if (tid == 0) off_[512] = cntB;
    __syncthreads();
    for (int j = tid; j < 512; j += 256) {
        int n = n0 + j;
        if (n < N) {
            rowptr[n] = base + off_[j];
            dis[n]    = rsqrtf(1.0f + (float)cnt_[j]);
        }
    }
    // emit s0 = bf16(dis * x) for this bucket's nodes (coalesced)
    {
        int nmax = min(512, N - n0);
        for (int idx = tid; idx < nmax * 16; idx += 256) {
            int nl = idx >> 4, f4 = idx & 15;
            float d  = rsqrtf(1.0f + (float)cnt_[nl]);
            float4 v = ((const float4*)(x + (size_t)(n0 + nl) * HF))[f4];
            ushort4 pk;
            pk.x = f2bf(d * v.x); pk.y = f2bf(d * v.y);
            pk.z = f2bf(d * v.z); pk.w = f2bf(d * v.w);
            *(ushort4*)&s0[(size_t)(n0 + nl) * HF + f4 * 4] = pk;
        }
    }
    if (cntB <= CAP) {
        for (u32 i = tid; i < cntB; i += 256) {
            u32 p   = part[base + i];
            u32 pos = atomicAdd(&cur[p >> 17], 1u);
            outb[pos] = p & 0x1FFFFu;
        }
        __syncthreads();
        for (u32 i = tid; i < cntB; i += 256)
            eidx[base + i] = (int)outb[i];
    } else {
        int j0 = 0;
        while (j0 < 512) {
            int j1 = j0 + 1;
            while (j1 < 512 && off_[j1 + 1] - off_[j0] <= CAP) ++j1;
            u32 p0 = off_[j0], p1 = off_[j1];
            for (u32 i = tid; i < cntB; i += 256) {
                u32 p  = part[base + i];
                u32 lc = p >> 17;
                if (lc >= (u32)j0 && lc < (u32)j1) {
                    u32 pos = atomicAdd(&cur[lc], 1u);
                    outb[pos - p0] = p & 0x1FFFFu;
                }
            }
            __syncthreads();
            for (u32 i = tid; i < p1 - p0; i += 256)
                eidx[base + p0 + i] = (int)outb[i];
            __syncthreads();
            j0 = j1;
        }
    }
}

// ---- CSR gather: pure closed-neighborhood sum, bf16 in / bf16 out ----------
// t[n] = Sum_{r in nbrs(n) + self} hs[r]. No dis/bias/relu here (k_trans does
// that with 64x LDS reuse — in-gather matvecs measured 2x slower, R5/R7).
// One wave per node; 4 quarter-waves each load a full 128B bf16 row.
__global__ __launch_bounds__(256) void k_gather(const u32* __restrict__ rowptr,
                                                const int* __restrict__ eidx,
                                                const u32* __restrict__ hs,   // bf16 pairs
                                                unsigned short* __restrict__ outbf,
                                                int N, int E) {
    const int tid  = threadIdx.x;
    const int wv   = tid >> 6;
    const int lane = tid & 63;
    const int q    = lane >> 4;      // quarter 0..3
    const int f4   = lane & 15;      // feature quad
    const int n    = blockIdx.x * 4 + wv;
    if (n >= N) return;

    u32 start = rowptr[n];
    u32 end   = (n + 1 < N) ? rowptr[n + 1] : (u32)E;
    float4 acc = float4{0.f, 0.f, 0.f, 0.f};

    u32 e = start + q;
    for (; e + 12 < end; e += 16) {          // 4 edges per quarter per iter
        int r0 = eidx[e], r1 = eidx[e + 4], r2 = eidx[e + 8], r3 = eidx[e + 12];
        uint2 w0 = ((const uint2*)(hs + (size_t)r0 * 32))[f4];
        uint2 w1 = ((const uint2*)(hs + (size_t)r1 * 32))[f4];
        uint2 w2 = ((const uint2*)(hs + (size_t)r2 * 32))[f4];
        uint2 w3 = ((const uint2*)(hs + (size_t)r3 * 32))[f4];
        acc.x += (bfl(w0.x) + bfl(w1.x)) + (bfl(w2.x) + bfl(w3.x));
        acc.y += (bfh(w0.x) + bfh(w1.x)) + (bfh(w2.x) + bfh(w3.x));
        acc.z += (bfl(w0.y) + bfl(w1.y)) + (bfl(w2.y) + bfl(w3.y));
        acc.w += (bfh(w0.y) + bfh(w1.y)) + (bfh(w2.y) + bfh(w3.y));
    }
    for (; e < end; e += 4) {
        int r = eidx[e];
        uint2 w = ((const uint2*)(hs + (size_t)r * 32))[f4];
        acc.x += bfl(w.x); acc.y += bfh(w.x);
        acc.z += bfl(w.y); acc.w += bfh(w.y);
    }
    if (q == 0) {                            // self-loop
        uint2 w = ((const uint2*)(hs + (size_t)n * 32))[f4];
        acc.x += bfl(w.x); acc.y += bfh(w.x);
        acc.z += bfl(w.y); acc.w += bfh(w.y);
    }
    acc.x += __shfl_xor(acc.x, 32); acc.y += __shfl_xor(acc.y, 32);
    acc.z += __shfl_xor(acc.z, 32); acc.w += __shfl_xor(acc.w, 32);
    acc.x += __shfl_xor(acc.x, 16); acc.y += __shfl_xor(acc.y, 16);
    acc.z += __shfl_xor(acc.z, 16); acc.w += __shfl_xor(acc.w, 16);

    if (q == 0) {
        ushort4 pk;
        pk.x = f2bf(acc.x); pk.y = f2bf(acc.y);
        pk.z = f2bf(acc.z); pk.w = f2bf(acc.w);
        *(ushort4*)&outbf[(size_t)n * HF + f4 * 4] = pk;
    }
}

// ---- tiled transform: OUT = post( dis[n]*(T[N,64] @ W[64,64]) + b ) --------
// OUTSCALE=1: out = bf16( dis * relu(...) )   (pre-scaled messages)
// OUTSCALE=0: out = bf16( relu(...) )         (pool input)
// __launch_bounds__(256,4): cap VGPRs at 128 (R8 measured 256 VGPR -> 8.4%
// occupancy, 57.5us for ~6us of roofline). Partial unroll bounds in-flight
// ds_read_b128.
template <int OUTSCALE>
__global__ __launch_bounds__(256, 4) void k_trans(const unsigned short* __restrict__ T,
                                                  const float* __restrict__ W,
                                                  const float* __restrict__ dis,
                                                  const float* __restrict__ bias,
                                                  unsigned short* __restrict__ OUT, int N) {
    __shared__ float ws[64 * 64];
    __shared__ float xs[64 * 68];
    const int tid  = threadIdx.x;
    const int row0 = blockIdx.x * 64;

#pragma unroll
    for (int i = 0; i < 4; ++i) {
        int idx4 = i * 256 + tid;
        *(float4*)&ws[idx4 * 4] = ((const float4*)W)[idx4];
    }
#pragma unroll
    for (int i = 0; i < 4; ++i) {
        int idx4 = i * 256 + tid;
        int r    = idx4 >> 4;
        int kk   = (idx4 & 15) << 2;
        float4 v = float4{0.f, 0.f, 0.f, 0.f};
        int row  = row0 + r;
        if (row < N) {
            ushort4 pk = ((const ushort4*)(T + (size_t)row * HF))[idx4 & 15];
            v.x = bf2f(pk.x); v.y = bf2f(pk.y);
            v.z = bf2f(pk.z); v.w = bf2f(pk.w);
        }
        *(float4*)&xs[r * 68 + kk] = v;
    }
    __syncthreads();

    const int rg = tid >> 4;
    const int cg = tid & 15;
    float4 a0 = float4{0.f, 0.f, 0.f, 0.f};
    float4 a1 = a0, a2 = a0, a3 = a0;

#pragma unroll 8
    for (int k = 0; k < 64; ++k) {
        float4 wv = *(float4*)&ws[k * 64 + cg * 4];
        float  x0 = xs[(rg * 4 + 0) * 68 + k];
        float  x1 = xs[(rg * 4 + 1) * 68 + k];
        float  x2 = xs[(rg * 4 + 2) * 68 + k];
        float  x3 = xs[(rg * 4 + 3) * 68 + k];
        a0.x += x0 * wv.x; a0.y += x0 * wv.y; a0.z += x0 * wv.z; a0.w += x0 * wv.w;
        a1.x += x1 * wv.x; a1.y += x1 * wv.y; a1.z += x1 * wv.z; a1.w += x1 * wv.w;
        a2.x += x2 * wv.x; a2.y += x2 * wv.y; a2.z += x2 * wv.z; a2.w += x2 * wv.w;
        a3.x += x3 * wv.x; a3.y += x3 * wv.y; a3.z += x3 * wv.z; a3.w += x3 * wv.w;
    }

    float4 bv = ((const float4*)bias)[cg];
    float4 accs[4] = {a0, a1, a2, a3};
#pragma unroll
    for (int j = 0; j < 4; ++j) {
        int row = row0 + rg * 4 + j;
        if (row < N) {
            float d = dis[row];
            float4 a = accs[j];
            a.x = fmaxf(d * a.x + bv.x, 0.f);
            a.y = fmaxf(d * a.y + bv.y, 0.f);
            a.z = fmaxf(d * a.z + bv.z, 0.f);
            a.w = fmaxf(d * a.w + bv.w, 0.f);
            float sc = OUTSCALE ? d : 1.0f;
            ushort4 pk;
            pk.x = f2bf(sc * a.x); pk.y = f2bf(sc * a.y);
            pk.z = f2bf(sc * a.z); pk.w = f2bf(sc * a.w);
            *(ushort4*)&OUT[(size_t)row * HF + cg * 4] = pk;
        }
    }
}

// ---- fused mean-pool + MLP head: one block per graph -----------------------
__device__ __forceinline__ int lower_bound(const int* __restrict__ a, int n, int key) {
    int lo = 0, hi = n;
    while (lo < hi) { int mid = (lo + hi) >> 1; if (a[mid] < key) lo = mid + 1; else hi = mid; }
    return lo;
}

__global__ __launch_bounds__(256) void k_poolhead(const u32* __restrict__ h2,  // bf16 pairs
                                                  const int* __restrict__ batch,
                                                  const float* __restrict__ Wl1,
                                                  const float* __restrict__ bl1,
                                                  const float* __restrict__ Wl2,
                                                  const float* __restrict__ bl2,
                                                  float* __restrict__ out, int N) {
    __shared__ float red[4][64];
    __shared__ float gm[64];
    const int g    = blockIdx.x;
    const int lane = threadIdx.x & 63;
    const int w    = threadIdx.x >> 6;
    int s = lower_bound(batch, N, g);
    int e = lower_bound(batch, N, g + 1);
    float acc = 0.f;
    for (int n = s + w; n < e; n += 4) {
        u32 wv = h2[(size_t)n * 32 + (lane >> 1)];
        acc += (lane & 1) ? bfh(wv) : bfl(wv);
    }
    red[w][lane] = acc;
    __syncthreads();
    if (w == 0) {
        float t = red[0][lane] + red[1][lane] + red[2][lane] + red[3][lane];
        gm[lane] = t / fmaxf((float)(e - s), 1.0f);
    }
    __syncthreads();
    if (w == 0 && lane < 32) {
        float a = bl1[lane];
#pragma unroll
        for (int k = 0; k < 64; ++k) a += gm[k] * Wl1[k * 32 + lane];
        a = fmaxf(a, 0.f);
        float l0 = a * Wl2[2 * lane];
        float l1 = a * Wl2[2 * lane + 1];
#pragma unroll
        for (int o = 1; o < 32; o <<= 1) {
            l0 += __shfl_xor(l0, o);
            l1 += __shfl_xor(l1, o);
        }
        if (lane == 0) {
            l0 += bl2[0]; l1 += bl2[1];
            float m   = fmaxf(l0, l1);
            float lse = m + logf(expf(l0 - m) + expf(l1 - m));
            out[2 * g]     = l0 - lse;
            out[2 * g + 1] = l1 - lse;
        }
    }
}

// ---- driver ----------------------------------------------------------------
extern "C" void kernel_launch(void* const* d_in, const int* in_sizes, int n_in,
                              void* d_out, int out_size, void* d_ws, size_t ws_size,
                              hipStream_t stream) {
    const float* x   = (const float*)d_in[0];
    const int*   ei  = (const int*)d_in[1];
    const int*   bi  = (const int*)d_in[2];
    const float* W1  = (const float*)d_in[3];
    const float* b1  = (const float*)d_in[4];
    const float* W2  = (const float*)d_in[5];
    const float* b2  = (const float*)d_in[6];
    const float* Wl1 = (const float*)d_in[7];
    const float* bl1 = (const float*)d_in[8];
    const float* Wl2 = (const float*)d_in[9];
    const float* bl2 = (const float*)d_in[10];
    float* out = (float*)d_out;

    const int N = in_sizes[0] / HF;
    const int E = in_sizes[1] / 2;
    const int* rows = ei;
    const int* cols = ei + E;
    const int NB = (N + BSZ - 1) / BSZ;

    // workspace (4B units). Two bf16 N x 64 regions:
    //   RA: s0 (place2 out, gather1 in) -> h1s (trans1 out, gather2 in)
    //       -> h2 (trans2 out, poolhead in)
    //   RB: part (dead after place2) -> t1 (gather1 out, trans1 in)
    //       -> t2 (gather2 out, trans2 in)
    float* ws = (float*)d_ws;
    size_t o = 0;
    float* dis    = ws + o; o += ((size_t)N + 63) / 64 * 64;
    unsigned short* RA = (unsigned short*)(ws + o); o += (size_t)N * 32;
    unsigned short* RB = (unsigned short*)(ws + o); o += (size_t)N * 32;  // >= E u32s
    u32*   part   = (u32*)RB;
    u32*   rowptr = (u32*)(ws + o); o += ((size_t)N + 63) / 64 * 64;
    int*   eidx   = (int*)(ws + o); o += (size_t)E;
    u32*   gbh    = (u32*)(ws + o); o += 256;
    u32*   done   = (u32*)(ws + o); o += 64;
    u32*   bscan  = (u32*)(ws + o); o += 320;
    u32*   gcurb  = (u32*)(ws + o); o += 256;

    const int tb = (N + 63) / 64;

    // CSR build (+ s0 emission inside place2)
    k_zero<<<2, 256, 0, stream>>>(gbh, 256 + 64);             // gbh + done
    k_bhist<<<256, 256, 0, stream>>>(cols, gbh, done, bscan, gcurb, E, NB);
    k_part<<<(E + PCHUNK - 1) / PCHUNK, 256, 0, stream>>>(rows, cols, gcurb, part, E);
    k_place2<<<NB, 256, 0, stream>>>(bscan, part, x, rowptr, dis, RA, eidx, N);

    // layer 1: t1 = sum(s0); h1s = bf16( dis * relu( dis*(t1@W1) + b1 ) )
    k_gather<<<(N + 3) / 4, 256, 0, stream>>>(rowptr, eidx, (const u32*)RA, RB, N, E);
    k_trans<1><<<tb, 256, 0, stream>>>(RB, W1, dis, b1, RA, N);
    // layer 2: t2 = sum(h1s); h2 = bf16( relu( dis*(t2@W2) + b2 ) )
    k_gather<<<(N + 3) / 4, 256, 0, stream>>>(rowptr, eidx, (const u32*)RA, RB, N, E);
    k_trans<0><<<tb, 256, 0, stream>>>(RB, W2, dis, b2, RA, N);

    // mean pool + head
    k_poolhead<<<256, 256, 0, stream>>>((const u32*)RA, bi, Wl1, bl1, Wl2, bl2, out, N);
}